// Round 13
// baseline (85.667 us; speedup 1.0000x reference)
//
#include <hip/hip_runtime.h>
#include <math.h>

#define BB 8
#define NCC 1024
#define NTT 1024
#define HH 128
#define DYY 32
#define NTB 16                   // 512 blocks x 512 threads
#define LOG2E 1.44269504088896340736f

typedef _Float16 half8 __attribute__((ext_vector_type(8)));
typedef float f32x4 __attribute__((ext_vector_type(4)));

// r13: phase-2 Y staging deleted. Y has NO reuse through LDS (global->LDS->
// reg->frag, same wave, 1:1) -- the B-frag gather (lane(tl,g) holds
// Y[8g+i][tl]) goes DIRECT global->reg with identical coalescing (16 tl-lanes
// = 64B runs, 4 g-rows/instr, L1-hot) and identical f16 cvt. -32 DS/wave,
// -16 VGPR staging buffer. xc staging moved to disjoint XCW arena, issued
// right after L0 -> latency hides under the whole MLP (regs->LDS immediately,
// r9 short-live-range lesson). B-frag values bit-identical to r12 => absmax
// must stay exactly 0.00390625 (correctness probe of the new indexing).
// Phase-1 L1/L2 MFMA f16x2 (r12, proven: absmax unchanged vs f32 MLP).
//
// LDS arenas (5616 floats = 22.5 KB):
//   HB[0,2112) RED[2112,2496) XCW[2496,5568) SIGL[5568,5616)
//   epilogue: CMB[0,4224) SL[4224,4352) alias HB/RED/XCW-front; the barrier
//   after the MFMA loop fences all xcw/HB reads before CMB deposits.
#define HB 0
#define RED 2112
#define XCW 2496
#define SIGL 5568
#define SMEM_SZ 5616
#define CMB 0
#define SL 4224
#define HSTRIDE 132

__global__ __launch_bounds__(512, 2) void k_fused(const float* __restrict__ xc,
                                                  const float* __restrict__ yc,
                                                  const float* __restrict__ xt,
                                                  const float* __restrict__ W0,
                                                  const float* __restrict__ b0,
                                                  const float* __restrict__ W1,
                                                  const float* __restrict__ b1,
                                                  const float* __restrict__ W2,
                                                  const float* __restrict__ b2,
                                                  const float* __restrict__ W3,
                                                  const float* __restrict__ b3,
                                                  float* __restrict__ out) {
    const int tid = threadIdx.x;
    const int phys = blockIdx.x;
    const int bid = (phys & 7) * 64 + (phys >> 3);   // XCD swizzle (proven)
    const int t0 = bid * NTB;
    const int b = bid >> 6;              // 64 blocks per batch
    const int wv = tid >> 6;             // wave 0..7
    const int lane = tid & 63;

    __shared__ float smem[SMEM_SZ];

    const float4* __restrict__ xcG4 = (const float4*)(xc + (size_t)b * NCC * 3);

    // ================= phase 1: MLP =================
    const int jg = tid >> 4;             // L0/L3 mapping
    const int p = tid & 15;
    const int j0 = jg * 4;
    float* hrow = smem + HB + p * HSTRIDE;

    // ---- L0 (VALU, cheap) ----
    {
        const float* xr = xt + (size_t)(t0 + p) * 3;
        const float x0 = xr[0], x1 = xr[1], x2 = xr[2];
        const float4* W0v = (const float4*)W0;
        const float4 w0a = W0v[jg], w0b = W0v[32 + jg], w0c = W0v[64 + jg];
        const float4 bb0 = ((const float4*)b0)[jg];
        float4 h0;
        h0.x = fmaxf(fmaf(x0, w0a.x, fmaf(x1, w0b.x, fmaf(x2, w0c.x, bb0.x))), 0.f);
        h0.y = fmaxf(fmaf(x0, w0a.y, fmaf(x1, w0b.y, fmaf(x2, w0c.y, bb0.y))), 0.f);
        h0.z = fmaxf(fmaf(x0, w0a.z, fmaf(x1, w0b.z, fmaf(x2, w0c.z, bb0.z))), 0.f);
        h0.w = fmaxf(fmaf(x0, w0a.w, fmaf(x1, w0b.w, fmaf(x2, w0c.w, bb0.w))), 0.f);
        *(float4*)(hrow + j0) = h0;
    }

    // ---- stage xc EARLY into disjoint wave-private XCW: latency hides under
    //      the whole MLP; regs -> LDS immediately (no long live range) ----
    {
        float* xcw = smem + XCW + wv * 384;
        if (lane < 48) {
            float4 tx0 = xcG4[wv * 96 + lane];
            float4 tx1 = xcG4[wv * 96 + 48 + lane];
            ((float4*)xcw)[lane] = tx0;
            ((float4*)xcw)[lane + 48] = tx1;
        }
    }
    __syncthreads();                     // h(L0) visible

    // ---- L1, L2: MFMA f16x2, W gathered from global (r12, proven) ----
    {
        const int mtl = lane & 15;       // A m-index (point) AND B n-index
        const int mg = lane >> 4;        // k-group 0..3
        const int jcol = wv * 16 + mtl;  // this lane's output column

#pragma unroll
        for (int l = 0; l < 2; ++l) {
            const float* __restrict__ Wg = (l == 0) ? W1 : W2;
            const float* __restrict__ bi = (l == 0) ? b1 : b2;
            f32x4 dac;
            {
                const float bj = bi[jcol];
                dac[0] = bj; dac[1] = bj; dac[2] = bj; dac[3] = bj;
            }
            float w[8];
#pragma unroll
            for (int i = 0; i < 8; ++i) w[i] = Wg[(mg * 8 + i) * HH + jcol];
#pragma unroll
            for (int c = 0; c < 4; ++c) {
                float wn[8];
                if (c < 3) {
#pragma unroll
                    for (int i = 0; i < 8; ++i)
                        wn[i] = Wg[((c + 1) * 32 + mg * 8 + i) * HH + jcol];
                }
                float hv[8];             // A: h[point=mtl][k=32c+8mg+i]
                *(float4*)hv =
                    *(const float4*)(smem + HB + mtl * HSTRIDE + c * 32 + mg * 8);
                *(float4*)(hv + 4) =
                    *(const float4*)(smem + HB + mtl * HSTRIDE + c * 32 + mg * 8 + 4);
                half8 a0, a1, bf0, bf1;
#pragma unroll
                for (int i = 0; i < 8; ++i) {
                    const _Float16 ah = (_Float16)hv[i];
                    a0[i] = ah;
                    a1[i] = (_Float16)(hv[i] - (float)ah);
                    const _Float16 wh = (_Float16)w[i];
                    bf0[i] = wh;
                    bf1[i] = (_Float16)(w[i] - (float)wh);
                }
                dac = __builtin_amdgcn_mfma_f32_16x16x32_f16(a0, bf0, dac, 0, 0, 0);
                dac = __builtin_amdgcn_mfma_f32_16x16x32_f16(a0, bf1, dac, 0, 0, 0);
                dac = __builtin_amdgcn_mfma_f32_16x16x32_f16(a1, bf0, dac, 0, 0, 0);
                if (c < 3) {
#pragma unroll
                    for (int i = 0; i < 8; ++i) w[i] = wn[i];
                }
            }
            __syncthreads();             // all waves done reading h(prev)
#pragma unroll
            for (int r = 0; r < 4; ++r)  // D[m=4mg+r][n=mtl] -> h[point][jcol]
                smem[HB + (mg * 4 + r) * HSTRIDE + jcol] = fmaxf(dac[r], 0.f);
            __syncthreads();             // h(l) visible
        }
    }

    // ---- L3 + exp -> sig*log2e ----
    {
        const float4 o4 = *(const float4*)(hrow + j0);   // h2[p][4jg..+4]
        const float4* W3v = (const float4*)W3;
        const float4 wr0 = W3v[jg * 3 + 0];
        const float4 wr1 = W3v[jg * 3 + 1];
        const float4 wr2 = W3v[jg * 3 + 2];
        float p0 = o4.x * wr0.x + o4.y * wr0.w + o4.z * wr1.z + o4.w * wr2.y;
        float p1 = o4.x * wr0.y + o4.y * wr1.x + o4.z * wr1.w + o4.w * wr2.z;
        float p2 = o4.x * wr0.z + o4.y * wr1.y + o4.z * wr2.x + o4.w * wr2.w;
        p0 += __shfl_xor(p0, 16, 64);
        p0 += __shfl_xor(p0, 32, 64);
        p1 += __shfl_xor(p1, 16, 64);
        p1 += __shfl_xor(p1, 32, 64);
        p2 += __shfl_xor(p2, 16, 64);
        p2 += __shfl_xor(p2, 32, 64);
        if (lane < 16) {
            smem[RED + wv * 48 + lane * 3 + 0] = p0;
            smem[RED + wv * 48 + lane * 3 + 1] = p1;
            smem[RED + wv * 48 + lane * 3 + 2] = p2;
        }
    }
    __syncthreads();
    if (tid < 48) {
        const int r = tid / 3, cix = tid - r * 3;
        float v = b3[cix];
#pragma unroll
        for (int g2 = 0; g2 < 8; ++g2) v += smem[RED + g2 * 48 + r * 3 + cix];
        smem[SIGL + r * 3 + cix] = __expf(v) * LOG2E;
    }
    __syncthreads();                     // sigl ready

    // ========== phase 2: E on VALU, einsum on MFMA, Y direct global->frag ====
    const int tl = lane & 15;            // target (A m-index) AND B n-index (d)
    const int g = lane >> 4;             // k-group 0..3

    const float s0 = smem[SIGL + tl * 3 + 0];
    const float s1 = smem[SIGL + tl * 3 + 1];
    const float s2 = smem[SIGL + tl * 3 + 2];
    const float* ar = xt + (size_t)(t0 + tl) * 3;
    const float a0 = ar[0], a1 = ar[1], a2 = ar[2];

    const float* xcw = smem + XCW + wv * 384;        // staged before the MLP
    // lane's Y row base: rows wv*128 + g*8 (+ c*32 + i), column tl / 16+tl
    const float* __restrict__ yB =
        yc + (size_t)b * NCC * DYY + (size_t)(wv * 128 + g * 8) * DYY + tl;

    f32x4 acc0 = {0.f, 0.f, 0.f, 0.f};
    f32x4 acc1 = {0.f, 0.f, 0.f, 0.f};
    float l = 0.f;

#pragma unroll
    for (int c = 0; c < 4; ++c) {
        // B-frags direct from global (f32 -> f16); 16 loads, 64B-coalesced
        float by0[8], by1[8];
#pragma unroll
        for (int i = 0; i < 8; ++i) {
            by0[i] = yB[(c * 32 + i) * DYY];
            by1[i] = yB[(c * 32 + i) * DYY + 16];
        }

        float xv[24];                    // this lane's 8 xc rows (broadcast LDS)
        {
            const float4* xr4 = (const float4*)(xcw + (c * 32 + g * 8) * 3);
#pragma unroll
            for (int q = 0; q < 6; ++q) *(float4*)(xv + q * 4) = xr4[q];
        }
        half8 af, bf0, bf1;              // A-frag: E[t=tl][k=8g+i]
#pragma unroll
        for (int i = 0; i < 8; ++i) {
            const float d0 = xv[i * 3 + 0] - a0;
            const float d1 = xv[i * 3 + 1] - a1;
            const float d2 = xv[i * 3 + 2] - a2;
            const float pp = fmaf(s0, d0 * d0, fmaf(s1, d1 * d1, s2 * (d2 * d2)));
            const _Float16 eh = (_Float16)exp2f(-pp);
            af[i] = eh;
            l += (float)eh;              // denominator from the SAME f16 E
            bf0[i] = (_Float16)by0[i];
            bf1[i] = (_Float16)by1[i];
        }
        acc0 = __builtin_amdgcn_mfma_f32_16x16x32_f16(af, bf0, acc0, 0, 0, 0);
        acc1 = __builtin_amdgcn_mfma_f32_16x16x32_f16(af, bf1, acc1, 0, 0, 0);
    }

    // l: reduce over the 4 k-groups -> full 128-n sum per target
    l += __shfl_xor(l, 16, 64);
    l += __shfl_xor(l, 32, 64);

    __syncthreads();                     // all xcw/HB reads done; CMB aliases
#pragma unroll
    for (int r = 0; r < 4; ++r) {        // D[m=4g+r][n=tl] ; m=target? no:
        // D[m][n]: n=lane&15 (=d col tl / 16+tl), m=4*(lane>>4)+r (=target)
        smem[CMB + wv * 528 + (g * 4 + r) * 33 + tl] = acc0[r];
        smem[CMB + wv * 528 + (g * 4 + r) * 33 + 16 + tl] = acc1[r];
    }
    if (lane < 16) smem[SL + wv * 16 + lane] = l;
    __syncthreads();
    {
        const int t = tid >> 5, d = tid & 31;   // each thread owns one output
        float s = 0.f, ls = 0.f;
#pragma unroll
        for (int w = 0; w < 8; ++w) {
            s += smem[CMB + w * 528 + t * 33 + d];
            ls += smem[SL + w * 16 + t];
        }
        out[(size_t)(t0 + t) * DYY + d] = s / ls;
    }
}

extern "C" void kernel_launch(void* const* d_in, const int* in_sizes, int n_in,
                              void* d_out, int out_size, void* d_ws, size_t ws_size,
                              hipStream_t stream) {
    const float* xc = (const float*)d_in[0];
    const float* yc = (const float*)d_in[1];
    const float* xt = (const float*)d_in[2];
    const float* W0 = (const float*)d_in[3];
    const float* b0 = (const float*)d_in[4];
    const float* W1 = (const float*)d_in[5];
    const float* b1 = (const float*)d_in[6];
    const float* W2 = (const float*)d_in[7];
    const float* b2 = (const float*)d_in[8];
    const float* W3 = (const float*)d_in[9];
    const float* b3 = (const float*)d_in[10];
    float* out = (float*)d_out;

    k_fused<<<dim3(BB * NTT / NTB), dim3(512), 0, stream>>>(xc, yc, xt, W0, b0,
                                                            W1, b1, W2, b2, W3,
                                                            b3, out);
}

// Round 14
// 85.015 us; speedup vs baseline: 1.0077x; 1.0077x over previous
//
#include <hip/hip_runtime.h>
#include <math.h>

#define BB 8
#define NCC 1024
#define NTT 1024
#define HH 128
#define DYY 32
#define NTB 16                   // 512 blocks x 512 threads
#define LOG2E 1.44269504088896340736f

typedef _Float16 half8 __attribute__((ext_vector_type(8)));
typedef float f32x4 __attribute__((ext_vector_type(4)));

// r14: latency/barrier skeleton cuts (r13 showed DS/staging is NOT the
// residual: Y-LDS deletion was neutral at ~20us kernel).
//  1. h ping-pong HB0/HB1: writeback goes to the OTHER buffer -> one barrier
//     per layer instead of two (9 -> 7 barriers).
//  2. W chunk-0 prefetch across the preceding barrier (8 VGPR, one short
//     segment -- R4's proven wA0/wA1 pattern, NOT r9's long-range mistake).
//  3. Phase-2 explicit distance-1 Y pipeline (+16 transient VGPR).
// Numerics identical to r12/r13 => absmax must stay exactly 0.00390625.
//
// LDS arenas (7728 floats = 30.9 KB):
//   HB0[0,2112) HB1[2112,4224) RED[4224,4608) XCW[4608,7680) SIGL[7680,7728)
//   epilogue: CMB[0,4224) SL[4224,4352) alias HB*/RED (dead); XCW reads are
//   fenced by the post-phase-2 barrier before CMB deposits; SIGL disjoint.
#define HB0 0
#define HB1 2112
#define RED 4224
#define XCW 4608
#define SIGL 7680
#define SMEM_SZ 7728
#define CMB 0
#define SL 4224
#define HSTRIDE 132

__global__ __launch_bounds__(512, 2) void k_fused(const float* __restrict__ xc,
                                                  const float* __restrict__ yc,
                                                  const float* __restrict__ xt,
                                                  const float* __restrict__ W0,
                                                  const float* __restrict__ b0,
                                                  const float* __restrict__ W1,
                                                  const float* __restrict__ b1,
                                                  const float* __restrict__ W2,
                                                  const float* __restrict__ b2,
                                                  const float* __restrict__ W3,
                                                  const float* __restrict__ b3,
                                                  float* __restrict__ out) {
    const int tid = threadIdx.x;
    const int phys = blockIdx.x;
    const int bid = (phys & 7) * 64 + (phys >> 3);   // XCD swizzle (proven)
    const int t0 = bid * NTB;
    const int b = bid >> 6;              // 64 blocks per batch
    const int wv = tid >> 6;             // wave 0..7
    const int lane = tid & 63;

    __shared__ float smem[SMEM_SZ];

    const float4* __restrict__ xcG4 = (const float4*)(xc + (size_t)b * NCC * 3);

    // ================= phase 1: MLP =================
    const int jg = tid >> 4;             // L0/L3 mapping
    const int p = tid & 15;
    const int j0 = jg * 4;

    // ---- L0 (VALU, cheap) ----
    {
        const float* xr = xt + (size_t)(t0 + p) * 3;
        const float x0 = xr[0], x1 = xr[1], x2 = xr[2];
        const float4* W0v = (const float4*)W0;
        const float4 w0a = W0v[jg], w0b = W0v[32 + jg], w0c = W0v[64 + jg];
        const float4 bb0 = ((const float4*)b0)[jg];
        float4 h0;
        h0.x = fmaxf(fmaf(x0, w0a.x, fmaf(x1, w0b.x, fmaf(x2, w0c.x, bb0.x))), 0.f);
        h0.y = fmaxf(fmaf(x0, w0a.y, fmaf(x1, w0b.y, fmaf(x2, w0c.y, bb0.y))), 0.f);
        h0.z = fmaxf(fmaf(x0, w0a.z, fmaf(x1, w0b.z, fmaf(x2, w0c.z, bb0.z))), 0.f);
        h0.w = fmaxf(fmaf(x0, w0a.w, fmaf(x1, w0b.w, fmaf(x2, w0c.w, bb0.w))), 0.f);
        *(float4*)(smem + HB0 + p * HSTRIDE + j0) = h0;
    }

    // ---- stage xc EARLY (disjoint XCW; latency hides under the MLP) ----
    {
        float* xcw = smem + XCW + wv * 384;
        if (lane < 48) {
            float4 tx0 = xcG4[wv * 96 + lane];
            float4 tx1 = xcG4[wv * 96 + 48 + lane];
            ((float4*)xcw)[lane] = tx0;
            ((float4*)xcw)[lane + 48] = tx1;
        }
    }

    // ---- L1, L2: MFMA f16x2, W from global; ping-pong h, 1 barrier/layer ----
    {
        const int mtl = lane & 15;       // A m-index (point) AND B n-index
        const int mg = lane >> 4;        // k-group 0..3
        const int jcol = wv * 16 + mtl;  // this lane's output column

        // prefetch L1 chunk-0 W across the L0 barrier (short live range)
        float w[8];
#pragma unroll
        for (int i = 0; i < 8; ++i) w[i] = W1[(mg * 8 + i) * HH + jcol];
        __syncthreads();                 // h(L0) + xcw visible

        float* hsrc = smem + HB0;
        float* hdst = smem + HB1;
#pragma unroll
        for (int l = 0; l < 2; ++l) {
            const float* __restrict__ Wg = (l == 0) ? W1 : W2;
            const float* __restrict__ bi = (l == 0) ? b1 : b2;
            f32x4 dac;
            {
                const float bj = bi[jcol];
                dac[0] = bj; dac[1] = bj; dac[2] = bj; dac[3] = bj;
            }
#pragma unroll
            for (int c = 0; c < 4; ++c) {
                float wn[8];
                if (c < 3) {             // distance-1 W prefetch
#pragma unroll
                    for (int i = 0; i < 8; ++i)
                        wn[i] = Wg[((c + 1) * 32 + mg * 8 + i) * HH + jcol];
                }
                float hv[8];             // A: h[point=mtl][k=32c+8mg+i]
                *(float4*)hv =
                    *(const float4*)(hsrc + mtl * HSTRIDE + c * 32 + mg * 8);
                *(float4*)(hv + 4) =
                    *(const float4*)(hsrc + mtl * HSTRIDE + c * 32 + mg * 8 + 4);
                half8 a0, a1, bf0, bf1;
#pragma unroll
                for (int i = 0; i < 8; ++i) {
                    const _Float16 ah = (_Float16)hv[i];
                    a0[i] = ah;
                    a1[i] = (_Float16)(hv[i] - (float)ah);
                    const _Float16 wh = (_Float16)w[i];
                    bf0[i] = wh;
                    bf1[i] = (_Float16)(w[i] - (float)wh);
                }
                dac = __builtin_amdgcn_mfma_f32_16x16x32_f16(a0, bf0, dac, 0, 0, 0);
                dac = __builtin_amdgcn_mfma_f32_16x16x32_f16(a0, bf1, dac, 0, 0, 0);
                dac = __builtin_amdgcn_mfma_f32_16x16x32_f16(a1, bf0, dac, 0, 0, 0);
                if (c < 3) {
#pragma unroll
                    for (int i = 0; i < 8; ++i) w[i] = wn[i];
                }
            }
            // writeback to the OTHER buffer: no conflict with hsrc readers
#pragma unroll
            for (int r = 0; r < 4; ++r)  // D[m=4mg+r][n=mtl] -> h[point][jcol]
                hdst[(mg * 4 + r) * HSTRIDE + jcol] = fmaxf(dac[r], 0.f);
            if (l == 0) {                // prefetch L2 chunk-0 W across barrier
#pragma unroll
                for (int i = 0; i < 8; ++i) w[i] = W2[(mg * 8 + i) * HH + jcol];
            }
            __syncthreads();             // hdst visible; hsrc now dead
            float* tmp = hsrc; hsrc = hdst; hdst = tmp;
        }
    }

    // ---- L3 + exp -> sig*log2e (h2 lives in HB0 after two swaps) ----
    {
        const float4 o4 = *(const float4*)(smem + HB0 + p * HSTRIDE + j0);
        const float4* W3v = (const float4*)W3;
        const float4 wr0 = W3v[jg * 3 + 0];
        const float4 wr1 = W3v[jg * 3 + 1];
        const float4 wr2 = W3v[jg * 3 + 2];
        float p0 = o4.x * wr0.x + o4.y * wr0.w + o4.z * wr1.z + o4.w * wr2.y;
        float p1 = o4.x * wr0.y + o4.y * wr1.x + o4.z * wr1.w + o4.w * wr2.z;
        float p2 = o4.x * wr0.z + o4.y * wr1.y + o4.z * wr2.x + o4.w * wr2.w;
        p0 += __shfl_xor(p0, 16, 64);
        p0 += __shfl_xor(p0, 32, 64);
        p1 += __shfl_xor(p1, 16, 64);
        p1 += __shfl_xor(p1, 32, 64);
        p2 += __shfl_xor(p2, 16, 64);
        p2 += __shfl_xor(p2, 32, 64);
        if (lane < 16) {
            smem[RED + wv * 48 + lane * 3 + 0] = p0;
            smem[RED + wv * 48 + lane * 3 + 1] = p1;
            smem[RED + wv * 48 + lane * 3 + 2] = p2;
        }
    }
    __syncthreads();
    if (tid < 48) {
        const int r = tid / 3, cix = tid - r * 3;
        float v = b3[cix];
#pragma unroll
        for (int g2 = 0; g2 < 8; ++g2) v += smem[RED + g2 * 48 + r * 3 + cix];
        smem[SIGL + r * 3 + cix] = __expf(v) * LOG2E;
    }
    __syncthreads();                     // sigl ready

    // ========== phase 2: E on VALU, einsum on MFMA, Y direct, pipelined ======
    const int tl = lane & 15;            // target (A m-index) AND B n-index (d)
    const int g = lane >> 4;             // k-group 0..3

    const float s0 = smem[SIGL + tl * 3 + 0];
    const float s1 = smem[SIGL + tl * 3 + 1];
    const float s2 = smem[SIGL + tl * 3 + 2];
    const float* ar = xt + (size_t)(t0 + tl) * 3;
    const float a0 = ar[0], a1 = ar[1], a2 = ar[2];

    const float* xcw = smem + XCW + wv * 384;        // staged before the MLP
    const float* __restrict__ yB =
        yc + (size_t)b * NCC * DYY + (size_t)(wv * 128 + g * 8) * DYY + tl;

    f32x4 acc0 = {0.f, 0.f, 0.f, 0.f};
    f32x4 acc1 = {0.f, 0.f, 0.f, 0.f};
    float l = 0.f;

    float by0[8], by1[8];                // chunk-c Y values
#pragma unroll
    for (int i = 0; i < 8; ++i) {
        by0[i] = yB[i * DYY];
        by1[i] = yB[i * DYY + 16];
    }

#pragma unroll
    for (int c = 0; c < 4; ++c) {
        float bn0[8], bn1[8];
        if (c < 3) {                     // distance-1 Y prefetch
#pragma unroll
            for (int i = 0; i < 8; ++i) {
                bn0[i] = yB[((c + 1) * 32 + i) * DYY];
                bn1[i] = yB[((c + 1) * 32 + i) * DYY + 16];
            }
        }

        float xv[24];                    // this lane's 8 xc rows (broadcast LDS)
        {
            const float4* xr4 = (const float4*)(xcw + (c * 32 + g * 8) * 3);
#pragma unroll
            for (int q = 0; q < 6; ++q) *(float4*)(xv + q * 4) = xr4[q];
        }
        half8 af, bf0, bf1;              // A-frag: E[t=tl][k=8g+i]
#pragma unroll
        for (int i = 0; i < 8; ++i) {
            const float d0 = xv[i * 3 + 0] - a0;
            const float d1 = xv[i * 3 + 1] - a1;
            const float d2 = xv[i * 3 + 2] - a2;
            const float pp = fmaf(s0, d0 * d0, fmaf(s1, d1 * d1, s2 * (d2 * d2)));
            const _Float16 eh = (_Float16)exp2f(-pp);
            af[i] = eh;
            l += (float)eh;              // denominator from the SAME f16 E
            bf0[i] = (_Float16)by0[i];
            bf1[i] = (_Float16)by1[i];
        }
        acc0 = __builtin_amdgcn_mfma_f32_16x16x32_f16(af, bf0, acc0, 0, 0, 0);
        acc1 = __builtin_amdgcn_mfma_f32_16x16x32_f16(af, bf1, acc1, 0, 0, 0);

        if (c < 3) {
#pragma unroll
            for (int i = 0; i < 8; ++i) { by0[i] = bn0[i]; by1[i] = bn1[i]; }
        }
    }

    // l: reduce over the 4 k-groups -> full 128-n sum per target
    l += __shfl_xor(l, 16, 64);
    l += __shfl_xor(l, 32, 64);

    __syncthreads();                     // all xcw reads done; CMB aliases
#pragma unroll
    for (int r = 0; r < 4; ++r) {
        // D[m][n]: n=lane&15 (=d col tl / 16+tl), m=4*(lane>>4)+r (=target)
        smem[CMB + wv * 528 + (g * 4 + r) * 33 + tl] = acc0[r];
        smem[CMB + wv * 528 + (g * 4 + r) * 33 + 16 + tl] = acc1[r];
    }
    if (lane < 16) smem[SL + wv * 16 + lane] = l;
    __syncthreads();
    {
        const int t = tid >> 5, d = tid & 31;   // each thread owns one output
        float s = 0.f, ls = 0.f;
#pragma unroll
        for (int w = 0; w < 8; ++w) {
            s += smem[CMB + w * 528 + t * 33 + d];
            ls += smem[SL + w * 16 + t];
        }
        out[(size_t)(t0 + t) * DYY + d] = s / ls;
    }
}

extern "C" void kernel_launch(void* const* d_in, const int* in_sizes, int n_in,
                              void* d_out, int out_size, void* d_ws, size_t ws_size,
                              hipStream_t stream) {
    const float* xc = (const float*)d_in[0];
    const float* yc = (const float*)d_in[1];
    const float* xt = (const float*)d_in[2];
    const float* W0 = (const float*)d_in[3];
    const float* b0 = (const float*)d_in[4];
    const float* W1 = (const float*)d_in[5];
    const float* b1 = (const float*)d_in[6];
    const float* W2 = (const float*)d_in[7];
    const float* b2 = (const float*)d_in[8];
    const float* W3 = (const float*)d_in[9];
    const float* b3 = (const float*)d_in[10];
    float* out = (float*)d_out;

    k_fused<<<dim3(BB * NTT / NTB), dim3(512), 0, stream>>>(xc, yc, xt, W0, b0,
                                                            W1, b1, W2, b2, W3,
                                                            b3, out);
}